// Round 8
// baseline (268.656 us; speedup 1.0000x reference)
//
#include <hip/hip_runtime.h>

#define LAM 0.5f
#define MU 0.1f
#define RHO 0.05f
#define CLS 10
#define ROWS 256
#define SG 16          // s-values per block
#define L2E  1.4426950408889634f
#define HL2E 0.7213475204444817f
#define EINV 0.36787944117144233f
#define AGENT __HIP_MEMORY_SCOPE_AGENT

typedef const __attribute__((address_space(1))) char gchar;
typedef __attribute__((address_space(3))) char lchar;

__device__ __forceinline__ float waveReduceSum(float v) {
#pragma unroll
    for (int m = 1; m < 64; m <<= 1) v += __shfl_xor(v, m, 64);
    return v;
}

// Stage 2560 B (64 rows x 10 floats) per wave: global -> LDS direct DMA.
// Wave slices are PRIVATE (thread tid reads row tid from its own wave's slice),
// so no __syncthreads is needed anywhere in the s-loop.
__device__ __forceinline__ void dmaTile(const float4* srcBase, float* dstBase,
                                        int wid, int lane) {
    const float4* s = srcBase + wid * 160;
    float* d = dstBase + wid * 640;
    __builtin_amdgcn_global_load_lds((gchar*)(const char*)(s + lane),
                                     (lchar*)(char*)d, 16, 0, 0);
    __builtin_amdgcn_global_load_lds((gchar*)(const char*)(s + 64 + lane),
                                     (lchar*)(char*)(d + 256), 16, 0, 0);
    if (lane < 32)
        __builtin_amdgcn_global_load_lds((gchar*)(const char*)(s + 128 + lane),
                                         (lchar*)(char*)(d + 512), 16, 0, 0);
}

// Round-4 main loop (proven ~60us: 2048 blocks, 7/CU, depth-1 DMA pipeline)
// + round-7 corrected in-kernel elect reduction (proven absmax 0).
__global__ __launch_bounds__(256) void fused_kernel(
    const float* __restrict__ noise, const float* __restrict__ pred,
    const int* __restrict__ tgt, float* __restrict__ ws,
    float* __restrict__ out, int B, int S) {
    __shared__ float buf0[ROWS * CLS];   // 10240 B
    __shared__ float buf1[ROWS * CLS];   // 10240 B
    __shared__ float part[4][SG * 3];
    __shared__ float red[4];
    __shared__ float scred[2];
    __shared__ unsigned flagA, flagB;

    const int tid = threadIdx.x;
    const int lane = tid & 63, wid = tid >> 6;
    const int nChunks = B / ROWS;               // 256
    const int chunk = (int)blockIdx.x % nChunks;
    const int sg = (int)blockIdx.x / nChunks;   // 0..7
    const int rowBase = chunk * ROWS;
    const int s0 = sg * SG;

    float* wstarPart = ws;                      // [256]
    float* sres2     = ws + 256;                // [384][16]
    unsigned* cnts   = (unsigned*)(ws + 6400);  // stride-32 padded counters
    float* partials  = ws + 8192;               // [256 chunks][384] chunk-major

    const int t = tgt[rowBase + tid];           // only non-DMA global load
    __builtin_amdgcn_sched_barrier(0);

    const size_t sStride4 = (size_t)B * CLS / 4;
    const float4* noiseT = (const float4*)(noise + (size_t)rowBase * CLS)
                           + (size_t)s0 * sStride4;

    dmaTile((const float4*)(pred + (size_t)rowBase * CLS), buf0, wid, lane);
    dmaTile(noiseT, buf1, wid, lane);
    asm volatile("s_waitcnt vmcnt(3)" ::: "memory");   // tgt + pred done
    __builtin_amdgcn_sched_barrier(0);

    // ---- logp from buf0 (wave-private) ----
    float x[CLS];
    {
        const float2* r2 = (const float2*)(buf0 + tid * CLS);
#pragma unroll
        for (int j = 0; j < 5; j++) { float2 v = r2[j]; x[2*j] = v.x; x[2*j+1] = v.y; }
    }
    float mx = x[0];
#pragma unroll
    for (int c = 1; c < CLS; c++) mx = fmaxf(mx, x[c]);
    float z = 0.f;
#pragma unroll
    for (int c = 0; c < CLS; c++) z += __expf(x[c] - mx);
    float lse = mx + __logf(z);

    float lp[CLS], lpk[CLS], kk[CLS], bias[CLS];
    float xt = 0.f;
#pragma unroll
    for (int c = 0; c < CLS; c++) {
        bool e = (c == t);
        float lpv = x[c] - lse;
        lp[c] = lpv;
        kk[c] = e ? EINV : 1.f;
        lpk[c] = lpv * kk[c];
        bias[c] = e ? L2E : 0.f;
        xt += e ? x[c] : 0.f;
    }
    {
        float rce = waveReduceSum(lse - xt);
        if (lane == 0) red[wid] = rce;
    }

    const float4* srcNext = noiseT + sStride4;

    // softmax(n+oh): pl = exp2(fma(n,HL2E,bias)) = exp(n/2+oh);
    // LAM-term uses pl; full term e = pl^2 * k (k = e^{-oh}).
#define BODY(CUR, NXT, SI)                                                     \
    {                                                                          \
        const int si = (SI);                                                   \
        if (si < SG - 1) {                                                     \
            dmaTile(srcNext, (NXT), wid, lane);                                \
            srcNext += sStride4;                                               \
            asm volatile("s_waitcnt vmcnt(3)" ::: "memory");                   \
        } else {                                                               \
            asm volatile("s_waitcnt vmcnt(0)" ::: "memory");                   \
        }                                                                      \
        __builtin_amdgcn_sched_barrier(0);                                     \
        float nn[CLS];                                                         \
        {                                                                      \
            const float2* r2 = (const float2*)((CUR) + tid * CLS);             \
            _Pragma("unroll")                                                  \
            for (int j = 0; j < 5; j++) {                                      \
                float2 v = r2[j]; nn[2*j] = v.x; nn[2*j+1] = v.y;              \
            }                                                                  \
        }                                                                      \
        float Z = 0.f, Zl = 0.f, dot = 0.f, dotl = 0.f, sq = 0.f;              \
        _Pragma("unroll")                                                      \
        for (int c = 0; c < CLS; c++) {                                        \
            float a  = fmaf(nn[c], HL2E, bias[c]);                             \
            float pl = exp2f(a);                                               \
            float t1 = pl * pl;                                                \
            Zl += pl;                                                          \
            dotl = fmaf(pl, lp[c], dotl);                                      \
            Z    = fmaf(t1, kk[c], Z);                                         \
            dot  = fmaf(t1, lpk[c], dot);                                      \
            sq   = fmaf(nn[c], nn[c], sq);                                     \
        }                                                                      \
        float rw  = waveReduceSum(__fdividef(dot, Z));                         \
        float rwt = waveReduceSum(__fdividef(dotl, Zl));                       \
        float rn2 = waveReduceSum(sq);                                         \
        if (lane == 0) {                                                       \
            part[wid][si * 3 + 0] = rw;                                        \
            part[wid][si * 3 + 1] = rwt;                                       \
            part[wid][si * 3 + 2] = rn2;                                       \
        }                                                                      \
    }

    for (int sb = 0; sb < SG; sb += 2) {
        BODY(buf1, buf0, sb);
        BODY(buf0, buf1, sb + 1);
    }
#undef BODY

    // ---- block partials -> global (coalesced, agent scope) ----
    __syncthreads();
    if (tid < SG * 3) {   // 48
        float v = part[0][tid] + part[1][tid] + part[2][tid] + part[3][tid];
        __hip_atomic_store(&partials[(size_t)chunk * 384 + sg * 48 + tid], v,
                           __ATOMIC_RELAXED, AGENT);
    }
    if (sg == 0 && tid == 255)
        __hip_atomic_store(&wstarPart[chunk], red[0] + red[1] + red[2] + red[3],
                           __ATOMIC_RELAXED, AGENT);
    __syncthreads();   // barrier drains vmcnt -> this block's stores complete

    // ---- stage 1 elect: per chunk-group (16 chunks x 8 sg = 128 blocks) ----
    const int cg = chunk >> 4;   // 16 groups
    if (tid == 0) {
        __threadfence();
        unsigned old = __hip_atomic_fetch_add(&cnts[cg * 32], 1u,
                                              __ATOMIC_ACQ_REL, AGENT);
        flagA = (old == 127u);   // last of the 128 -> all group data visible
    }
    __syncthreads();
    if (flagA) {
        float acc0 = 0.f, acc1 = 0.f;
        const float* pbase = partials + (size_t)(cg * 16) * 384;
#pragma unroll 4
        for (int c = 0; c < 16; ++c) {
            acc0 += __hip_atomic_load(&pbase[c * 384 + tid], __ATOMIC_RELAXED, AGENT);
            if (tid < 128)
                acc1 += __hip_atomic_load(&pbase[c * 384 + 256 + tid], __ATOMIC_RELAXED, AGENT);
        }
        __hip_atomic_store(&sres2[(size_t)tid * 16 + cg], acc0, __ATOMIC_RELAXED, AGENT);
        if (tid < 128)
            __hip_atomic_store(&sres2[(size_t)(256 + tid) * 16 + cg], acc1,
                               __ATOMIC_RELAXED, AGENT);
        __syncthreads();   // drain stores before final counter
        if (tid == 0) {
            __threadfence();
            unsigned old2 = __hip_atomic_fetch_add(&cnts[16 * 32], 1u,
                                                   __ATOMIC_ACQ_REL, AGENT);
            flagB = (old2 == 15u);   // last of 16 group-elects
        }
        __syncthreads();
        // ---- stage 2 elect: finalize ----
        if (flagB) {
            float* sresL = buf0;   // reuse LDS (384 floats)
            for (int r = tid; r < 384; r += 256) {
                float v = 0.f;
#pragma unroll
                for (int q = 0; q < 16; ++q)
                    v += __hip_atomic_load(&sres2[(size_t)r * 16 + q],
                                           __ATOMIC_RELAXED, AGENT);
                sresL[r] = v;
            }
            float wv = __hip_atomic_load(&wstarPart[tid], __ATOMIC_RELAXED, AGENT);
            wv = waveReduceSum(wv);
            if (lane == 0) red[wid] = wv;
            __syncthreads();   // sresL + red ready
            float invB = 1.0f / (float)B;
            float wstar = (red[0] + red[1] + red[2] + red[3]) * invB;
            float local = 0.f;
            if (tid < S) {
                float w  = -sresL[3 * tid + 0] * invB;
                float wt = -sresL[3 * tid + 1] * invB;
                float n2 =  sresL[3 * tid + 2];
                float sc1 = fmaxf(wstar - wt, 0.f);
                float sc2 = fmaxf(wstar - w + MU * n2 * 0.5f, 0.f);
                float sc3 = fmaxf(wt - (1.f - LAM) * wstar + LAM * w
                                  + MU * LAM * (1.f - LAM) * n2 * 0.5f, 0.f);
                local = sc1 + sc2 + sc3;
            }
            if (tid < 128) {
                float rsc = waveReduceSum(local);
                if (lane == 0) scred[wid] = rsc;
            }
            __syncthreads();
            if (tid == 0) out[0] = wstar + RHO * (scred[0] + scred[1]);
        }
    }
}

extern "C" void kernel_launch(void* const* d_in, const int* in_sizes, int n_in,
                              void* d_out, int out_size, void* d_ws, size_t ws_size,
                              hipStream_t stream) {
    const float* pred  = (const float*)d_in[0];
    const int*   tgt   = (const int*)d_in[1];
    const float* noise = (const float*)d_in[2];
    float* out = (float*)d_out;

    int B = in_sizes[1];                 // 65536
    int S = in_sizes[2] / in_sizes[0];   // 128
    int nChunks = B / ROWS;              // 256
    int nSG = S / SG;                    // 8

    // zero the elect counters (byte offset 25600, 17 counters @ stride 128 B)
    hipMemsetAsync((char*)d_ws + 25600, 0, 2560, stream);

    fused_kernel<<<nSG * nChunks, 256, 0, stream>>>(noise, pred, tgt,
                                                    (float*)d_ws, out, B, S);
}

// Round 9
// 74.199 us; speedup vs baseline: 3.6208x; 3.6208x over previous
//
#include <hip/hip_runtime.h>

#define LAM 0.5f
#define MU 0.1f
#define RHO 0.05f
#define CLS 10
#define ROWS 256
#define SG 16          // s-values per block
#define L2E  1.4426950408889634f
#define HL2E 0.7213475204444817f
#define EINV 0.36787944117144233f

typedef const __attribute__((address_space(1))) char gchar;
typedef __attribute__((address_space(3))) char lchar;

__device__ __forceinline__ float waveReduceSum(float v) {
#pragma unroll
    for (int m = 1; m < 64; m <<= 1) v += __shfl_xor(v, m, 64);
    return v;
}

// Stage 2560 B (64 rows x 10 floats) per wave: global -> LDS direct DMA.
// Wave slices are PRIVATE (thread tid reads row tid from its own wave's slice),
// so no __syncthreads is needed anywhere in the kernel.
__device__ __forceinline__ void dmaTile(const float4* srcBase, float* dstBase,
                                        int wid, int lane) {
    const float4* s = srcBase + wid * 160;
    float* d = dstBase + wid * 640;
    __builtin_amdgcn_global_load_lds((gchar*)(const char*)(s + lane),
                                     (lchar*)(char*)d, 16, 0, 0);
    __builtin_amdgcn_global_load_lds((gchar*)(const char*)(s + 64 + lane),
                                     (lchar*)(char*)(d + 256), 16, 0, 0);
    if (lane < 32)
        __builtin_amdgcn_global_load_lds((gchar*)(const char*)(s + 128 + lane),
                                         (lchar*)(char*)(d + 512), 16, 0, 0);
}

// Main: round-4 depth-1 DMA pipeline, but LDS = EXACTLY 20480 B (2 buffers,
// nothing else) -> 8 blocks/CU = 32 waves/CU, grid 2048 = one exact round.
// Per-wave (si,k) partials live in a per-lane "keep" register (lane 3*si+k
// holds value k of iteration si; lane 48 holds the wave's wstar partial);
// one 48-lane global store per wave at the end. Zero barriers, zero atomics.
__global__ __launch_bounds__(256) void main_kernel(
    const float* __restrict__ noise, const float* __restrict__ pred,
    const int* __restrict__ tgt,
    float* __restrict__ wstarPart, float* __restrict__ partials, int B) {
    __shared__ float buf0[ROWS * CLS];   // 10240 B
    __shared__ float buf1[ROWS * CLS];   // 10240 B  (total 20480 exactly)

    const int tid = threadIdx.x;
    const int lane = tid & 63, wid = tid >> 6;
    const int nChunks = B / ROWS;               // 256
    const int chunk = (int)blockIdx.x % nChunks;
    const int sg = (int)blockIdx.x / nChunks;   // 0..7
    const int rowBase = chunk * ROWS;
    const int s0 = sg * SG;
    const int nPart = nChunks * 4;              // 1024

    const int t = tgt[rowBase + tid];           // only non-DMA global load
    __builtin_amdgcn_sched_barrier(0);

    const size_t sStride4 = (size_t)B * CLS / 4;
    const float4* noiseT = (const float4*)(noise + (size_t)rowBase * CLS)
                           + (size_t)s0 * sStride4;

    dmaTile((const float4*)(pred + (size_t)rowBase * CLS), buf0, wid, lane);
    dmaTile(noiseT, buf1, wid, lane);
    asm volatile("s_waitcnt vmcnt(3)" ::: "memory");   // tgt + pred done
    __builtin_amdgcn_sched_barrier(0);

    // ---- logp from buf0 (wave-private) ----
    float x[CLS];
    {
        const float2* r2 = (const float2*)(buf0 + tid * CLS);
#pragma unroll
        for (int j = 0; j < 5; j++) { float2 v = r2[j]; x[2*j] = v.x; x[2*j+1] = v.y; }
    }
    float mx = x[0];
#pragma unroll
    for (int c = 1; c < CLS; c++) mx = fmaxf(mx, x[c]);
    float z = 0.f;
#pragma unroll
    for (int c = 0; c < CLS; c++) z += __expf(x[c] - mx);
    float lse = mx + __logf(z);

    float lp[CLS], lpk[CLS], kk[CLS], bias[CLS];
    float xt = 0.f;
#pragma unroll
    for (int c = 0; c < CLS; c++) {
        bool e = (c == t);
        float lpv = x[c] - lse;
        lp[c] = lpv;
        kk[c] = e ? EINV : 1.f;
        lpk[c] = lpv * kk[c];
        bias[c] = e ? L2E : 0.f;
        xt += e ? x[c] : 0.f;
    }
    float keep;
    {
        float rce = waveReduceSum(lse - xt);
        keep = (lane == 48) ? rce : 0.f;
    }

    const float4* srcNext = noiseT + sStride4;

    // softmax(n+oh): pl = exp2(fma(n,HL2E,bias)) = exp(n/2+oh);
    // LAM-term uses pl; full term e = pl^2 * k (k = e^{-oh}).
#define BODY(CUR, NXT, SI)                                                     \
    {                                                                          \
        const int si = (SI);                                                   \
        if (si < SG - 1) {                                                     \
            dmaTile(srcNext, (NXT), wid, lane);                                \
            srcNext += sStride4;                                               \
            asm volatile("s_waitcnt vmcnt(3)" ::: "memory");                   \
        } else {                                                               \
            asm volatile("s_waitcnt vmcnt(0)" ::: "memory");                   \
        }                                                                      \
        __builtin_amdgcn_sched_barrier(0);                                     \
        float nn[CLS];                                                         \
        {                                                                      \
            const float2* r2 = (const float2*)((CUR) + tid * CLS);             \
            _Pragma("unroll")                                                  \
            for (int j = 0; j < 5; j++) {                                      \
                float2 v = r2[j]; nn[2*j] = v.x; nn[2*j+1] = v.y;              \
            }                                                                  \
        }                                                                      \
        float Z = 0.f, Zl = 0.f, dot = 0.f, dotl = 0.f, sq = 0.f;              \
        _Pragma("unroll")                                                      \
        for (int c = 0; c < CLS; c++) {                                        \
            float a  = fmaf(nn[c], HL2E, bias[c]);                             \
            float pl = exp2f(a);                                               \
            float t1 = pl * pl;                                                \
            Zl += pl;                                                          \
            dotl = fmaf(pl, lp[c], dotl);                                      \
            Z    = fmaf(t1, kk[c], Z);                                         \
            dot  = fmaf(t1, lpk[c], dot);                                      \
            sq   = fmaf(nn[c], nn[c], sq);                                     \
        }                                                                      \
        float rw  = waveReduceSum(__fdividef(dot, Z));                         \
        float rwt = waveReduceSum(__fdividef(dotl, Zl));                       \
        float rn2 = waveReduceSum(sq);                                         \
        keep = (lane == si * 3    ) ? rw  : keep;                              \
        keep = (lane == si * 3 + 1) ? rwt : keep;                              \
        keep = (lane == si * 3 + 2) ? rn2 : keep;                              \
    }

    for (int sb = 0; sb < SG; sb += 2) {
        BODY(buf1, buf0, sb);
        BODY(buf0, buf1, sb + 1);
    }
#undef BODY

    // ---- per-wave partials -> global: lane 3*si+k holds (si,k) value ----
    if (lane < SG * 3) {
        int si = lane / 3, k = lane - 3 * si;
        partials[(size_t)((s0 + si) * 3 + k) * nPart + chunk * 4 + wid] = keep;
    }
    if (sg == 0 && lane == 48)
        wstarPart[chunk * 4 + wid] = keep;
}

// Per-s reduction over 1024 wave-partials + hinge -> scPart[s].
// Each block also (redundantly) reduces wstarPart for its own wstar.
__global__ __launch_bounds__(256) void reduce_kernel(
    const float* __restrict__ partials, const float* __restrict__ wstarPart,
    float* __restrict__ scPart, float* __restrict__ wsum, int B, int nPart) {
    __shared__ float red[4][4];
    const int s = blockIdx.x, tid = threadIdx.x;
    const int lane = tid & 63, wid = tid >> 6;
    const float* p = partials + (size_t)s * 3 * nPart;
    float a = 0.f, b = 0.f, c = 0.f, wv = 0.f;
    for (int j = tid; j < nPart; j += 256) {
        a  += p[j];
        b  += p[nPart + j];
        c  += p[2 * nPart + j];
        wv += wstarPart[j];
    }
    a = waveReduceSum(a); b = waveReduceSum(b);
    c = waveReduceSum(c); wv = waveReduceSum(wv);
    if (lane == 0) { red[wid][0] = a; red[wid][1] = b; red[wid][2] = c; red[wid][3] = wv; }
    __syncthreads();
    if (tid == 0) {
        float ra = red[0][0] + red[1][0] + red[2][0] + red[3][0];
        float rb = red[0][1] + red[1][1] + red[2][1] + red[3][1];
        float rc = red[0][2] + red[1][2] + red[2][2] + red[3][2];
        float rw = red[0][3] + red[1][3] + red[2][3] + red[3][3];
        float invB = 1.0f / (float)B;
        float wstar = rw * invB;
        float w  = -ra * invB;
        float wt = -rb * invB;
        float n2 =  rc;
        float sc1 = fmaxf(wstar - wt, 0.f);
        float sc2 = fmaxf(wstar - w + MU * n2 * 0.5f, 0.f);
        float sc3 = fmaxf(wt - (1.f - LAM) * wstar + LAM * w
                          + MU * LAM * (1.f - LAM) * n2 * 0.5f, 0.f);
        scPart[s] = sc1 + sc2 + sc3;
        if (s == 0) wsum[0] = rw;
    }
}

// Finalize: out = wstar + RHO * sum(scPart).
__global__ __launch_bounds__(256) void finalize_kernel(
    const float* __restrict__ scPart, const float* __restrict__ wsum,
    float* __restrict__ out, int B, int S) {
    __shared__ float red[2];
    const int tid = threadIdx.x, lane = tid & 63, wid = tid >> 6;
    float v = (tid < S) ? scPart[tid] : 0.f;
    if (tid < 128) {
        float r = waveReduceSum(v);
        if (lane == 0) red[wid] = r;
    }
    __syncthreads();
    if (tid == 0)
        out[0] = wsum[0] / (float)B + RHO * (red[0] + red[1]);
}

extern "C" void kernel_launch(void* const* d_in, const int* in_sizes, int n_in,
                              void* d_out, int out_size, void* d_ws, size_t ws_size,
                              hipStream_t stream) {
    const float* pred  = (const float*)d_in[0];
    const int*   tgt   = (const int*)d_in[1];
    const float* noise = (const float*)d_in[2];
    float* out = (float*)d_out;

    int B = in_sizes[1];                 // 65536
    int S = in_sizes[2] / in_sizes[0];   // 128
    int nChunks = B / ROWS;              // 256
    int nSG = S / SG;                    // 8
    int nPart = nChunks * 4;             // 1024

    float* ws = (float*)d_ws;
    float* wstarPart = ws;               // [1024]
    float* scPart    = ws + 1024;        // [128]
    float* wsum      = ws + 1152;        // [1]
    float* partials  = ws + 2048;        // [384][1024]

    main_kernel<<<nSG * nChunks, 256, 0, stream>>>(noise, pred, tgt,
                                                   wstarPart, partials, B);
    reduce_kernel<<<S, 256, 0, stream>>>(partials, wstarPart, scPart, wsum,
                                         B, nPart);
    finalize_kernel<<<1, 256, 0, stream>>>(scPart, wsum, out, B, S);
}